// Round 5
// baseline (353.649 us; speedup 1.0000x reference)
//
#include <hip/hip_runtime.h>

// FP8FrozenLinear: out = x @ (dequant(W_fp8)*scale)^T + bias
// M=8192, K=4096, N=4096.
// Round 5: ROOT-CAUSE FIX — harness delivers weight_fp8 as bf16 or f32
// (fp8 unsupported transport dtype), NOT raw fp8 bytes. Detect on device
// (f32 storage of fp8 values => even uint16s all zero), decode accordingly.
// GEMM core = R3 (m97 structure, global_load_lds, linear LDS).
// Fused fallback covers the small-ws hypothesis.

#define TILE 128
#define BKK  64

typedef __attribute__((ext_vector_type(8))) __bf16 bfrag8;
typedef __attribute__((ext_vector_type(4))) float  f32x4;
typedef __attribute__((ext_vector_type(8))) short  s8v;

#define GLOBAL_AS(p) ((const __attribute__((address_space(1))) void*)(p))
#define LDS_AS(p)    ((__attribute__((address_space(3))) void*)(p))

__device__ inline unsigned short f2bf(float f) {
    union { float f; unsigned u; } v; v.f = f;
    unsigned r = v.u + 0x7FFFu + ((v.u >> 16) & 1u);   // RNE
    return (unsigned short)(r >> 16);
}
__device__ inline float bf2f(unsigned short u) {
    union { unsigned u; float f; } v; v.u = ((unsigned)u) << 16;
    return v.f;
}

// Detect W storage dtype. fp8 values converted to f32 have zero low-16
// mantissa bits -> even-indexed uint16s are ALL 0x0000. bf16 storage: even
// uint16s are bf16 weight values (all-zero over 64 samples ~ impossible).
// Returns 1 = f32 storage, 0 = bf16 storage.
__device__ inline int detect_w_f32(const void* w) {
    const unsigned short* u = (const unsigned short*)w;
    unsigned nz = 0;
#pragma unroll
    for (int i = 0; i < 64; ++i) nz |= u[2 * i];
    return nz == 0 ? 1 : 0;
}

__global__ void FP8FL_cvt_x(const float* __restrict__ x, short* __restrict__ xb, long n) {
    long i = ((long)blockIdx.x * blockDim.x + threadIdx.x) * 8;
    if (i >= n) return;
    float4 a = *(const float4*)(x + i);
    float4 b = *(const float4*)(x + i + 4);
    s8v r;
    r[0] = (short)f2bf(a.x); r[1] = (short)f2bf(a.y);
    r[2] = (short)f2bf(a.z); r[3] = (short)f2bf(a.w);
    r[4] = (short)f2bf(b.x); r[5] = (short)f2bf(b.y);
    r[6] = (short)f2bf(b.z); r[7] = (short)f2bf(b.w);
    *(s8v*)(xb + i) = r;
}

// W (bf16 or f32 storage of fp8-grid values) -> bf16 * scale
__global__ void FP8FL_cvt_w(const void* __restrict__ w, short* __restrict__ wb,
                            const float* __restrict__ scale_p, long n) {
    __shared__ int sdt;
    if (threadIdx.x == 0) sdt = detect_w_f32(w);
    __syncthreads();
    long i = ((long)blockIdx.x * blockDim.x + threadIdx.x) * 8;
    if (i >= n) return;
    const float s = scale_p[0];
    s8v r;
    if (sdt) {                                    // f32 storage
        const float* wf = (const float*)w;
        float4 a = *(const float4*)(wf + i);
        float4 b = *(const float4*)(wf + i + 4);
        r[0] = (short)f2bf(a.x * s); r[1] = (short)f2bf(a.y * s);
        r[2] = (short)f2bf(a.z * s); r[3] = (short)f2bf(a.w * s);
        r[4] = (short)f2bf(b.x * s); r[5] = (short)f2bf(b.y * s);
        r[6] = (short)f2bf(b.z * s); r[7] = (short)f2bf(b.w * s);
    } else {                                      // bf16 storage
        const unsigned short* wu = (const unsigned short*)w;
        s8v v = *(const s8v*)(wu + i);
#pragma unroll
        for (int j = 0; j < 8; ++j)
            r[j] = (short)f2bf(bf2f((unsigned short)v[j]) * s);
    }
    *(s8v*)(wb + i) = r;
}

// GEMM from pre-converted bf16 buffers (R3 / m97 structure, linear LDS).
// A: [M][K] bf16, B: [N][K] bf16. out[m][n] = sum_k A[m][k]*B[n][k] + bias[n]
__global__ void FP8FL_gemm(const short* __restrict__ A, const short* __restrict__ B,
                           const float* __restrict__ bias, float* __restrict__ C,
                           int M, int N, int K) {
    __shared__ short As[TILE * BKK];
    __shared__ short Bs[TILE * BKK];

    const int tid  = threadIdx.x;
    const int lane = tid & 63;
    const int wid  = tid >> 6;

    const int nwg = gridDim.x;
    const int bid = blockIdx.x;
    const int wg  = (nwg % 8 == 0) ? (bid % 8) * (nwg / 8) + (bid / 8) : bid;

    const int tiles_n = N / TILE;
    const int tm = wg / tiles_n, tn = wg % tiles_n;
    const long row0 = (long)tm * TILE;
    const long col0 = (long)tn * TILE;

    const int wm = wid >> 1, wn = wid & 1;

    f32x4 acc[4][4];
#pragma unroll
    for (int i = 0; i < 4; ++i)
#pragma unroll
        for (int j = 0; j < 4; ++j) acc[i][j] = (f32x4){0.f, 0.f, 0.f, 0.f};

    const int rl = lane & 15;
    const int g  = lane >> 4;

    for (int k0 = 0; k0 < K; k0 += BKK) {
        __syncthreads();
#pragma unroll
        for (int i = 0; i < 4; ++i) {
            int c  = i * 256 + tid;
            int r  = c >> 3;
            int ls = c & 7;
            const short* ga = A + ((size_t)(row0 + r) * K + k0 + ls * 8);
            const short* gb = B + ((size_t)(col0 + r) * K + k0 + ls * 8);
            int ldsoff = (i * 256 + wid * 64) * 16;
            __builtin_amdgcn_global_load_lds(GLOBAL_AS(ga), LDS_AS((char*)As + ldsoff), 16, 0, 0);
            __builtin_amdgcn_global_load_lds(GLOBAL_AS(gb), LDS_AS((char*)Bs + ldsoff), 16, 0, 0);
        }
        __syncthreads();

#pragma unroll
        for (int kk = 0; kk < 2; ++kk) {
            bfrag8 af[4], bfr[4];
            const int lsk = kk * 4 + g;
#pragma unroll
            for (int m = 0; m < 4; ++m) {
                int r  = wm * 64 + m * 16 + rl;
                af[m] = *(const bfrag8*)&As[r * 64 + lsk * 8];
            }
#pragma unroll
            for (int n = 0; n < 4; ++n) {
                int r  = wn * 64 + n * 16 + rl;
                bfr[n] = *(const bfrag8*)&Bs[r * 64 + lsk * 8];
            }
#pragma unroll
            for (int m = 0; m < 4; ++m)
#pragma unroll
                for (int n = 0; n < 4; ++n)
                    acc[m][n] = __builtin_amdgcn_mfma_f32_16x16x32_bf16(af[m], bfr[n], acc[m][n], 0, 0, 0);
        }
    }

    float bv[4];
#pragma unroll
    for (int n = 0; n < 4; ++n) bv[n] = bias[col0 + wn * 64 + n * 16 + rl];
#pragma unroll
    for (int m = 0; m < 4; ++m) {
#pragma unroll
        for (int j = 0; j < 4; ++j) {
            long r = row0 + wm * 64 + m * 16 + g * 4 + j;
            float* cp = C + r * (long)N + col0 + wn * 64 + rl;
#pragma unroll
            for (int n = 0; n < 4; ++n) cp[n * 16] = acc[m][n][j] + bv[n];
        }
    }
}

// Fused GEMM: reads x (f32) and W (bf16/f32, detected) directly, converts in
// registers, reg-staged to LDS (R4 transport). Covers small-ws case.
__global__ void FP8FL_gemm_fused(const float* __restrict__ X, const void* __restrict__ W,
                                 const float* __restrict__ scale_p,
                                 const float* __restrict__ bias, float* __restrict__ C,
                                 int M, int N, int K) {
    __shared__ short As[TILE * BKK];
    __shared__ short Bs[TILE * BKK];
    __shared__ int sdt;

    const int tid  = threadIdx.x;
    const int lane = tid & 63;
    const int wid  = tid >> 6;

    if (tid == 0) sdt = detect_w_f32(W);
    __syncthreads();
    const int wdt = sdt;
    const float s = scale_p[0];

    const int nwg = gridDim.x;
    const int bid = blockIdx.x;
    const int wg  = (nwg % 8 == 0) ? (bid % 8) * (nwg / 8) + (bid / 8) : bid;

    const int tiles_n = N / TILE;
    const int tm = wg / tiles_n, tn = wg % tiles_n;
    const long row0 = (long)tm * TILE;
    const long col0 = (long)tn * TILE;

    const int wm = wid >> 1, wn = wid & 1;

    f32x4 acc[4][4];
#pragma unroll
    for (int i = 0; i < 4; ++i)
#pragma unroll
        for (int j = 0; j < 4; ++j) acc[i][j] = (f32x4){0.f, 0.f, 0.f, 0.f};

    const int rl = lane & 15;
    const int g  = lane >> 4;

    for (int k0 = 0; k0 < K; k0 += BKK) {
        s8v va[4], vb[4];
#pragma unroll
        for (int i = 0; i < 4; ++i) {
            int c  = i * 256 + tid;
            int r  = c >> 3;
            int ls = c & 7;
            // A: x is f32 -> convert 8 elems
            {
                const float* xp = X + ((size_t)(row0 + r) * K + k0 + ls * 8);
                float4 a = *(const float4*)xp;
                float4 b = *(const float4*)(xp + 4);
                s8v t;
                t[0] = (short)f2bf(a.x); t[1] = (short)f2bf(a.y);
                t[2] = (short)f2bf(a.z); t[3] = (short)f2bf(a.w);
                t[4] = (short)f2bf(b.x); t[5] = (short)f2bf(b.y);
                t[6] = (short)f2bf(b.z); t[7] = (short)f2bf(b.w);
                va[i] = t;
            }
            // B: W is bf16 or f32 storage
            {
                size_t off = (size_t)(col0 + r) * K + k0 + ls * 8;
                s8v t;
                if (wdt) {
                    const float* wp = (const float*)W + off;
                    float4 a = *(const float4*)wp;
                    float4 b = *(const float4*)(wp + 4);
                    t[0] = (short)f2bf(a.x * s); t[1] = (short)f2bf(a.y * s);
                    t[2] = (short)f2bf(a.z * s); t[3] = (short)f2bf(a.w * s);
                    t[4] = (short)f2bf(b.x * s); t[5] = (short)f2bf(b.y * s);
                    t[6] = (short)f2bf(b.z * s); t[7] = (short)f2bf(b.w * s);
                } else {
                    const unsigned short* wp = (const unsigned short*)W + off;
                    s8v v = *(const s8v*)wp;
#pragma unroll
                    for (int j = 0; j < 8; ++j)
                        t[j] = (short)f2bf(bf2f((unsigned short)v[j]) * s);
                }
                vb[i] = t;
            }
        }
        __syncthreads();
#pragma unroll
        for (int i = 0; i < 4; ++i) {
            int c = i * 256 + tid;
            *(s8v*)((char*)As + (size_t)c * 16) = va[i];
            *(s8v*)((char*)Bs + (size_t)c * 16) = vb[i];
        }
        __syncthreads();

#pragma unroll
        for (int kk = 0; kk < 2; ++kk) {
            bfrag8 af[4], bfr[4];
            const int lsk = kk * 4 + g;
#pragma unroll
            for (int m = 0; m < 4; ++m) {
                int r  = wm * 64 + m * 16 + rl;
                af[m] = *(const bfrag8*)&As[r * 64 + lsk * 8];
            }
#pragma unroll
            for (int n = 0; n < 4; ++n) {
                int r  = wn * 64 + n * 16 + rl;
                bfr[n] = *(const bfrag8*)&Bs[r * 64 + lsk * 8];
            }
#pragma unroll
            for (int m = 0; m < 4; ++m)
#pragma unroll
                for (int n = 0; n < 4; ++n)
                    acc[m][n] = __builtin_amdgcn_mfma_f32_16x16x32_bf16(af[m], bfr[n], acc[m][n], 0, 0, 0);
        }
    }

    float bv[4];
#pragma unroll
    for (int n = 0; n < 4; ++n) bv[n] = bias[col0 + wn * 64 + n * 16 + rl];
#pragma unroll
    for (int m = 0; m < 4; ++m) {
#pragma unroll
        for (int j = 0; j < 4; ++j) {
            long r = row0 + wm * 64 + m * 16 + g * 4 + j;
            float* cp = C + r * (long)N + col0 + wn * 64 + rl;
#pragma unroll
            for (int n = 0; n < 4; ++n) cp[n * 16] = acc[m][n][j] + bv[n];
        }
    }
}

// Last-resort fallback (odd dims only).
__global__ void FP8FL_naive(const float* __restrict__ x, const void* __restrict__ w,
                            const float* __restrict__ scale_p, const float* __restrict__ bias,
                            float* __restrict__ out, int M, int N, int K) {
    __shared__ int sdt;
    if (threadIdx.x == 0) sdt = detect_w_f32(w);
    __syncthreads();
    long o = (long)blockIdx.x * blockDim.x + threadIdx.x;
    if (o >= (long)M * N) return;
    int m = (int)(o / N), n = (int)(o % N);
    const float* xr = x + (size_t)m * K;
    float acc = 0.f;
    if (sdt) {
        const float* wr = (const float*)w + (size_t)n * K;
        for (int k = 0; k < K; ++k) acc += xr[k] * wr[k];
    } else {
        const unsigned short* wr = (const unsigned short*)w + (size_t)n * K;
        for (int k = 0; k < K; ++k) acc += xr[k] * bf2f(wr[k]);
    }
    out[o] = acc * scale_p[0] + bias[n];
}

extern "C" void kernel_launch(void* const* d_in, const int* in_sizes, int n_in,
                              void* d_out, int out_size, void* d_ws, size_t ws_size,
                              hipStream_t stream) {
    const float* x     = (const float*)d_in[0];
    const void*  w     = d_in[1];
    const float* scale = (const float*)d_in[2];
    const float* bias  = (const float*)d_in[3];
    float*       out   = (float*)d_out;

    const int N = in_sizes[3];
    const int K = in_sizes[1] / N;
    const int M = in_sizes[0] / K;

    const bool dims_ok = (M % TILE == 0) && (N % TILE == 0) && (K % BKK == 0);
    const size_t need = (size_t)M * K * 2 + (size_t)N * K * 2;

    if (dims_ok && ws_size >= need) {
        short* xb = (short*)d_ws;
        short* wb = (short*)((char*)d_ws + (size_t)M * K * 2);
        long nx = (long)M * K;
        long nw = (long)N * K;
        FP8FL_cvt_x<<<(int)((nx / 8 + 255) / 256), 256, 0, stream>>>(x, xb, nx);
        FP8FL_cvt_w<<<(int)((nw / 8 + 255) / 256), 256, 0, stream>>>(w, wb, scale, nw);
        int grid = (M / TILE) * (N / TILE);
        FP8FL_gemm<<<grid, 256, 0, stream>>>(xb, wb, bias, out, M, N, K);
    } else if (dims_ok) {
        int grid = (M / TILE) * (N / TILE);
        FP8FL_gemm_fused<<<grid, 256, 0, stream>>>(x, w, scale, bias, out, M, N, K);
    } else {
        long total = (long)M * N;
        FP8FL_naive<<<(int)((total + 255) / 256), 256, 0, stream>>>(x, w, scale, bias, out, M, N, K);
    }
}

// Round 6
// 295.109 us; speedup vs baseline: 1.1984x; 1.1984x over previous
//
#include <hip/hip_runtime.h>

// FP8FrozenLinear: out = x @ (dequant(W)*scale)^T + bias   (W shipped as bf16/f32)
// M=8192, K=4096, N=4096.
// Round 6: 256x256 deep-pipelined GEMM (T2 swizzle + T3/T4 counted vmcnt + T5
// setprio), K-slice phases, uniform s_waitcnt vmcnt(4). Fallbacks: m97-style
// 128^2 (R5, verified), fused, naive.

#define TILE 128
#define BKK  64
#define BM256 256
#define BN256 256

typedef __attribute__((ext_vector_type(8))) __bf16 bfrag8;
typedef __attribute__((ext_vector_type(4))) float  f32x4;
typedef __attribute__((ext_vector_type(8))) short  s8v;

#define GLOBAL_AS(p) ((const __attribute__((address_space(1))) void*)(p))
#define LDS_AS(p)    ((__attribute__((address_space(3))) void*)(p))

__device__ inline unsigned short f2bf(float f) {
    union { float f; unsigned u; } v; v.f = f;
    unsigned r = v.u + 0x7FFFu + ((v.u >> 16) & 1u);   // RNE
    return (unsigned short)(r >> 16);
}
__device__ inline float bf2f(unsigned short u) {
    union { unsigned u; float f; } v; v.u = ((unsigned)u) << 16;
    return v.f;
}

// W storage dtype: f32 storage of fp8-grid values => even uint16s all zero.
__device__ inline int detect_w_f32(const void* w) {
    const unsigned short* u = (const unsigned short*)w;
    unsigned nz = 0;
#pragma unroll
    for (int i = 0; i < 64; ++i) nz |= u[2 * i];
    return nz == 0 ? 1 : 0;
}

__global__ void FP8FL_cvt_x(const float* __restrict__ x, short* __restrict__ xb, long n) {
    long i = ((long)blockIdx.x * blockDim.x + threadIdx.x) * 8;
    if (i >= n) return;
    float4 a = *(const float4*)(x + i);
    float4 b = *(const float4*)(x + i + 4);
    s8v r;
    r[0] = (short)f2bf(a.x); r[1] = (short)f2bf(a.y);
    r[2] = (short)f2bf(a.z); r[3] = (short)f2bf(a.w);
    r[4] = (short)f2bf(b.x); r[5] = (short)f2bf(b.y);
    r[6] = (short)f2bf(b.z); r[7] = (short)f2bf(b.w);
    *(s8v*)(xb + i) = r;
}

__global__ void FP8FL_cvt_w(const void* __restrict__ w, short* __restrict__ wb,
                            const float* __restrict__ scale_p, long n) {
    __shared__ int sdt;
    if (threadIdx.x == 0) sdt = detect_w_f32(w);
    __syncthreads();
    long i = ((long)blockIdx.x * blockDim.x + threadIdx.x) * 8;
    if (i >= n) return;
    const float s = scale_p[0];
    s8v r;
    if (sdt) {
        const float* wf = (const float*)w;
        float4 a = *(const float4*)(wf + i);
        float4 b = *(const float4*)(wf + i + 4);
        r[0] = (short)f2bf(a.x * s); r[1] = (short)f2bf(a.y * s);
        r[2] = (short)f2bf(a.z * s); r[3] = (short)f2bf(a.w * s);
        r[4] = (short)f2bf(b.x * s); r[5] = (short)f2bf(b.y * s);
        r[6] = (short)f2bf(b.z * s); r[7] = (short)f2bf(b.w * s);
    } else {
        const unsigned short* wu = (const unsigned short*)w;
        s8v v = *(const s8v*)(wu + i);
#pragma unroll
        for (int j = 0; j < 8; ++j)
            r[j] = (short)f2bf(bf2f((unsigned short)v[j]) * s);
    }
    *(s8v*)(wb + i) = r;
}

// ---------------- 256x256 deep-pipelined GEMM ----------------
// LDS map (byte offsets inside 128 KiB):
//   A slab: d*65536 + p*16384          (p = K-sub-slice 0/1, 32 cols each)
//   B slab: d*65536 + 32768 + p*16384
// Slab layout: [256 rows][4 slots of 16B], physical slot = j ^ ((row>>1)&3)
// where j = logical 8-col group. Staged linearly (chunk pc -> byte pc*16) with
// inverse-swizzled global source (same involution) — rule #21 both-sides.
__device__ inline void stage_pair256(const short* __restrict__ A, const short* __restrict__ B,
                                     long row0, long col0, int K, int kc,
                                     char* __restrict__ lds, int d, int p,
                                     int wid, int lane) {
    char* Asl = lds + d * 65536 + p * 16384;
    char* Bsl = lds + d * 65536 + 32768 + p * 16384;
#pragma unroll
    for (int i = 0; i < 2; ++i) {
        int pc = i * 512 + wid * 64 + lane;
        int r  = pc >> 2;
        int j  = (pc & 3) ^ ((r >> 1) & 3);
        const short* ga = A + (size_t)(row0 + r) * K + kc + j * 8;
        const short* gb = B + (size_t)(col0 + r) * K + kc + j * 8;
        char* da = Asl + (i * 512 + wid * 64) * 16;   // wave-uniform base
        char* db = Bsl + (i * 512 + wid * 64) * 16;
        __builtin_amdgcn_global_load_lds(GLOBAL_AS(ga), LDS_AS(da), 16, 0, 0);
        __builtin_amdgcn_global_load_lds(GLOBAL_AS(gb), LDS_AS(db), 16, 0, 0);
    }
}

__global__ __launch_bounds__(512, 2)
void FP8FL_gemm256(const short* __restrict__ A, const short* __restrict__ B,
                   const float* __restrict__ bias, float* __restrict__ C,
                   int M, int N, int K) {
    __shared__ char lds[131072];

    const int tid  = threadIdx.x;
    const int lane = tid & 63;
    const int wid  = tid >> 6;

    const int nwg = gridDim.x;
    const int bid = blockIdx.x;
    const int wg  = (nwg % 8 == 0) ? (bid % 8) * (nwg / 8) + (bid / 8) : bid;

    const int tiles_n = N / BN256;
    const long row0 = (long)(wg / tiles_n) * BM256;
    const long col0 = (long)(wg % tiles_n) * BN256;

    const int wm = wid >> 2, wn = wid & 3;      // 2x4 wave grid, 128x64 out each
    const int rl = lane & 15, g = lane >> 4;

    f32x4 acc[8][4];
#pragma unroll
    for (int m = 0; m < 8; ++m)
#pragma unroll
        for (int n = 0; n < 4; ++n) acc[m][n] = (f32x4){0.f, 0.f, 0.f, 0.f};

    const int NT = K / BKK;

    // Prologue: stage both slab-pairs of tile 0; wait for pair 0 only (4 in flight).
    stage_pair256(A, B, row0, col0, K, 0,  lds, 0, 0, wid, lane);
    stage_pair256(A, B, row0, col0, K, 32, lds, 0, 1, wid, lane);
    asm volatile("s_waitcnt vmcnt(4)" ::: "memory");
    __builtin_amdgcn_s_barrier();

    for (int t = 0; t < NT; ++t) {
        const int d = t & 1;
#pragma unroll
        for (int p = 0; p < 2; ++p) {
            // ds-read this phase's fragments (slab p of current buffer)
            const char* Asl = lds + d * 65536 + p * 16384;
            const char* Bsl = lds + d * 65536 + 32768 + p * 16384;
            bfrag8 af[8], bfv[4];
#pragma unroll
            for (int m = 0; m < 8; ++m) {
                int r  = wm * 128 + m * 16 + rl;
                int sl = g ^ ((r >> 1) & 3);
                af[m] = *(const bfrag8*)(Asl + (r * 4 + sl) * 16);
            }
#pragma unroll
            for (int n = 0; n < 4; ++n) {
                int r  = wn * 64 + n * 16 + rl;
                int sl = g ^ ((r >> 1) & 3);
                bfv[n] = *(const bfrag8*)(Bsl + (r * 4 + sl) * 16);
            }
            // prefetch: slab-pair (t+1, p) into the other buffer
            if (t + 1 < NT)
                stage_pair256(A, B, row0, col0, K, (t + 1) * BKK + p * 32,
                              lds, d ^ 1, p, wid, lane);

            __builtin_amdgcn_s_barrier();
            asm volatile("s_waitcnt lgkmcnt(0)" ::: "memory");
            __builtin_amdgcn_sched_barrier(0);
            __builtin_amdgcn_s_setprio(1);
#pragma unroll
            for (int m = 0; m < 8; ++m)
#pragma unroll
                for (int n = 0; n < 4; ++n)
                    acc[m][n] = __builtin_amdgcn_mfma_f32_16x16x32_bf16(af[m], bfv[n], acc[m][n], 0, 0, 0);
            __builtin_amdgcn_s_setprio(0);

            // counted drain: one slab-pair (4 loads) stays in flight — never 0 in-loop
            if (t + 1 < NT)      asm volatile("s_waitcnt vmcnt(4)" ::: "memory");
            else if (p == 0)     asm volatile("s_waitcnt vmcnt(0)" ::: "memory");
            __builtin_amdgcn_s_barrier();
        }
    }

    // Epilogue: C/D layout col = lane&15, row = (lane>>4)*4 + reg  [m89/m91]
    float bv[4];
#pragma unroll
    for (int n = 0; n < 4; ++n) bv[n] = bias[col0 + wn * 64 + n * 16 + rl];
#pragma unroll
    for (int m = 0; m < 8; ++m) {
#pragma unroll
        for (int jj = 0; jj < 4; ++jj) {
            long r = row0 + wm * 128 + m * 16 + g * 4 + jj;
            float* cp = C + r * (long)N + col0 + wn * 64 + rl;
#pragma unroll
            for (int n = 0; n < 4; ++n) cp[n * 16] = acc[m][n][jj] + bv[n];
        }
    }
}

// ---------------- m97-style 128^2 GEMM (R5, verified) — fallback ----------------
__global__ void FP8FL_gemm(const short* __restrict__ A, const short* __restrict__ B,
                           const float* __restrict__ bias, float* __restrict__ C,
                           int M, int N, int K) {
    __shared__ short As[TILE * BKK];
    __shared__ short Bs[TILE * BKK];

    const int tid  = threadIdx.x;
    const int lane = tid & 63;
    const int wid  = tid >> 6;

    const int nwg = gridDim.x;
    const int bid = blockIdx.x;
    const int wg  = (nwg % 8 == 0) ? (bid % 8) * (nwg / 8) + (bid / 8) : bid;

    const int tiles_n = N / TILE;
    const int tm = wg / tiles_n, tn = wg % tiles_n;
    const long row0 = (long)tm * TILE;
    const long col0 = (long)tn * TILE;

    const int wm = wid >> 1, wn = wid & 1;

    f32x4 acc[4][4];
#pragma unroll
    for (int i = 0; i < 4; ++i)
#pragma unroll
        for (int j = 0; j < 4; ++j) acc[i][j] = (f32x4){0.f, 0.f, 0.f, 0.f};

    const int rl = lane & 15;
    const int g  = lane >> 4;

    for (int k0 = 0; k0 < K; k0 += BKK) {
        __syncthreads();
#pragma unroll
        for (int i = 0; i < 4; ++i) {
            int c  = i * 256 + tid;
            int r  = c >> 3;
            int ls = c & 7;
            const short* ga = A + ((size_t)(row0 + r) * K + k0 + ls * 8);
            const short* gb = B + ((size_t)(col0 + r) * K + k0 + ls * 8);
            int ldsoff = (i * 256 + wid * 64) * 16;
            __builtin_amdgcn_global_load_lds(GLOBAL_AS(ga), LDS_AS((char*)As + ldsoff), 16, 0, 0);
            __builtin_amdgcn_global_load_lds(GLOBAL_AS(gb), LDS_AS((char*)Bs + ldsoff), 16, 0, 0);
        }
        __syncthreads();

#pragma unroll
        for (int kk = 0; kk < 2; ++kk) {
            bfrag8 af[4], bfr[4];
            const int lsk = kk * 4 + g;
#pragma unroll
            for (int m = 0; m < 4; ++m) {
                int r  = wm * 64 + m * 16 + rl;
                af[m] = *(const bfrag8*)&As[r * 64 + lsk * 8];
            }
#pragma unroll
            for (int n = 0; n < 4; ++n) {
                int r  = wn * 64 + n * 16 + rl;
                bfr[n] = *(const bfrag8*)&Bs[r * 64 + lsk * 8];
            }
#pragma unroll
            for (int m = 0; m < 4; ++m)
#pragma unroll
                for (int n = 0; n < 4; ++n)
                    acc[m][n] = __builtin_amdgcn_mfma_f32_16x16x32_bf16(af[m], bfr[n], acc[m][n], 0, 0, 0);
        }
    }

    float bv[4];
#pragma unroll
    for (int n = 0; n < 4; ++n) bv[n] = bias[col0 + wn * 64 + n * 16 + rl];
#pragma unroll
    for (int m = 0; m < 4; ++m) {
#pragma unroll
        for (int j = 0; j < 4; ++j) {
            long r = row0 + wm * 64 + m * 16 + g * 4 + j;
            float* cp = C + r * (long)N + col0 + wn * 64 + rl;
#pragma unroll
            for (int n = 0; n < 4; ++n) cp[n * 16] = acc[m][n][j] + bv[n];
        }
    }
}

// Fused GEMM (ws too small): reads x (f32) and W (bf16/f32) directly. R5-verified path.
__global__ void FP8FL_gemm_fused(const float* __restrict__ X, const void* __restrict__ W,
                                 const float* __restrict__ scale_p,
                                 const float* __restrict__ bias, float* __restrict__ C,
                                 int M, int N, int K) {
    __shared__ short As[TILE * BKK];
    __shared__ short Bs[TILE * BKK];
    __shared__ int sdt;

    const int tid  = threadIdx.x;
    const int lane = tid & 63;
    const int wid  = tid >> 6;

    if (tid == 0) sdt = detect_w_f32(W);
    __syncthreads();
    const int wdt = sdt;
    const float s = scale_p[0];

    const int nwg = gridDim.x;
    const int bid = blockIdx.x;
    const int wg  = (nwg % 8 == 0) ? (bid % 8) * (nwg / 8) + (bid / 8) : bid;

    const int tiles_n = N / TILE;
    const long row0 = (long)(wg / tiles_n) * TILE;
    const long col0 = (long)(wg % tiles_n) * TILE;

    const int wm = wid >> 1, wn = wid & 1;

    f32x4 acc[4][4];
#pragma unroll
    for (int i = 0; i < 4; ++i)
#pragma unroll
        for (int j = 0; j < 4; ++j) acc[i][j] = (f32x4){0.f, 0.f, 0.f, 0.f};

    const int rl = lane & 15;
    const int g  = lane >> 4;

    for (int k0 = 0; k0 < K; k0 += BKK) {
        s8v va[4], vb[4];
#pragma unroll
        for (int i = 0; i < 4; ++i) {
            int c  = i * 256 + tid;
            int r  = c >> 3;
            int ls = c & 7;
            {
                const float* xp = X + ((size_t)(row0 + r) * K + k0 + ls * 8);
                float4 a = *(const float4*)xp;
                float4 b = *(const float4*)(xp + 4);
                s8v t;
                t[0] = (short)f2bf(a.x); t[1] = (short)f2bf(a.y);
                t[2] = (short)f2bf(a.z); t[3] = (short)f2bf(a.w);
                t[4] = (short)f2bf(b.x); t[5] = (short)f2bf(b.y);
                t[6] = (short)f2bf(b.z); t[7] = (short)f2bf(b.w);
                va[i] = t;
            }
            {
                size_t off = (size_t)(col0 + r) * K + k0 + ls * 8;
                s8v t;
                if (wdt) {
                    const float* wp = (const float*)W + off;
                    float4 a = *(const float4*)wp;
                    float4 b = *(const float4*)(wp + 4);
                    t[0] = (short)f2bf(a.x * s); t[1] = (short)f2bf(a.y * s);
                    t[2] = (short)f2bf(a.z * s); t[3] = (short)f2bf(a.w * s);
                    t[4] = (short)f2bf(b.x * s); t[5] = (short)f2bf(b.y * s);
                    t[6] = (short)f2bf(b.z * s); t[7] = (short)f2bf(b.w * s);
                } else {
                    const unsigned short* wp = (const unsigned short*)W + off;
                    s8v v = *(const s8v*)wp;
#pragma unroll
                    for (int j = 0; j < 8; ++j)
                        t[j] = (short)f2bf(bf2f((unsigned short)v[j]) * s);
                }
                vb[i] = t;
            }
        }
        __syncthreads();
#pragma unroll
        for (int i = 0; i < 4; ++i) {
            int c = i * 256 + tid;
            *(s8v*)((char*)As + (size_t)c * 16) = va[i];
            *(s8v*)((char*)Bs + (size_t)c * 16) = vb[i];
        }
        __syncthreads();

#pragma unroll
        for (int kk = 0; kk < 2; ++kk) {
            bfrag8 af[4], bfr[4];
            const int lsk = kk * 4 + g;
#pragma unroll
            for (int m = 0; m < 4; ++m) {
                int r  = wm * 64 + m * 16 + rl;
                af[m] = *(const bfrag8*)&As[r * 64 + lsk * 8];
            }
#pragma unroll
            for (int n = 0; n < 4; ++n) {
                int r  = wn * 64 + n * 16 + rl;
                bfr[n] = *(const bfrag8*)&Bs[r * 64 + lsk * 8];
            }
#pragma unroll
            for (int m = 0; m < 4; ++m)
#pragma unroll
                for (int n = 0; n < 4; ++n)
                    acc[m][n] = __builtin_amdgcn_mfma_f32_16x16x32_bf16(af[m], bfr[n], acc[m][n], 0, 0, 0);
        }
    }

    float bv[4];
#pragma unroll
    for (int n = 0; n < 4; ++n) bv[n] = bias[col0 + wn * 64 + n * 16 + rl];
#pragma unroll
    for (int m = 0; m < 4; ++m) {
#pragma unroll
        for (int j = 0; j < 4; ++j) {
            long r = row0 + wm * 64 + m * 16 + g * 4 + j;
            float* cp = C + r * (long)N + col0 + wn * 64 + rl;
#pragma unroll
            for (int n = 0; n < 4; ++n) cp[n * 16] = acc[m][n][j] + bv[n];
        }
    }
}

// Last-resort fallback (odd dims).
__global__ void FP8FL_naive(const float* __restrict__ x, const void* __restrict__ w,
                            const float* __restrict__ scale_p, const float* __restrict__ bias,
                            float* __restrict__ out, int M, int N, int K) {
    __shared__ int sdt;
    if (threadIdx.x == 0) sdt = detect_w_f32(w);
    __syncthreads();
    long o = (long)blockIdx.x * blockDim.x + threadIdx.x;
    if (o >= (long)M * N) return;
    int m = (int)(o / N), n = (int)(o % N);
    const float* xr = x + (size_t)m * K;
    float acc = 0.f;
    if (sdt) {
        const float* wr = (const float*)w + (size_t)n * K;
        for (int k = 0; k < K; ++k) acc += xr[k] * wr[k];
    } else {
        const unsigned short* wr = (const unsigned short*)w + (size_t)n * K;
        for (int k = 0; k < K; ++k) acc += xr[k] * bf2f(wr[k]);
    }
    out[o] = acc * scale_p[0] + bias[n];
}

extern "C" void kernel_launch(void* const* d_in, const int* in_sizes, int n_in,
                              void* d_out, int out_size, void* d_ws, size_t ws_size,
                              hipStream_t stream) {
    const float* x     = (const float*)d_in[0];
    const void*  w     = d_in[1];
    const float* scale = (const float*)d_in[2];
    const float* bias  = (const float*)d_in[3];
    float*       out   = (float*)d_out;

    const int N = in_sizes[3];
    const int K = in_sizes[1] / N;
    const int M = in_sizes[0] / K;

    const size_t need = (size_t)M * K * 2 + (size_t)N * K * 2;
    const bool ws_ok   = ws_size >= need;
    const bool dims256 = (M % BM256 == 0) && (N % BN256 == 0) && (K % BKK == 0);
    const bool dims128 = (M % TILE == 0) && (N % TILE == 0) && (K % BKK == 0);

    if (ws_ok && (dims256 || dims128)) {
        short* xb = (short*)d_ws;
        short* wb = (short*)((char*)d_ws + (size_t)M * K * 2);
        long nx = (long)M * K;
        long nw = (long)N * K;
        FP8FL_cvt_x<<<(int)((nx / 8 + 255) / 256), 256, 0, stream>>>(x, xb, nx);
        FP8FL_cvt_w<<<(int)((nw / 8 + 255) / 256), 256, 0, stream>>>(w, wb, scale, nw);
        if (dims256) {
            int grid = (M / BM256) * (N / BN256);
            FP8FL_gemm256<<<grid, 512, 0, stream>>>(xb, wb, bias, out, M, N, K);
        } else {
            int grid = (M / TILE) * (N / TILE);
            FP8FL_gemm<<<grid, 256, 0, stream>>>(xb, wb, bias, out, M, N, K);
        }
    } else if (dims128) {
        int grid = (M / TILE) * (N / TILE);
        FP8FL_gemm_fused<<<grid, 256, 0, stream>>>(x, w, scale, bias, out, M, N, K);
    } else {
        long total = (long)M * N;
        FP8FL_naive<<<(int)((total + 255) / 256), 256, 0, stream>>>(x, w, scale, bias, out, M, N, K);
    }
}

// Round 7
// 274.851 us; speedup vs baseline: 1.2867x; 1.0737x over previous
//
#include <hip/hip_runtime.h>

// FP8FrozenLinear: out = x @ (dequant(W)*scale)^T + bias   (W shipped as bf16/f32)
// M=8192, K=4096, N=4096.
// Round 7: 256x256 GEMM, ONE phase per K-tile — all 24 frag ds_reads issued
// up-front so slab-1 reads drain under slab-0 MFMA (compiler partial lgkmcnt).
// One __syncthreads per tile (full-tile vmcnt slack makes the drain free).
// T2 slot swizzle kept (conflicts=0 verified R6). Fallbacks unchanged.

#define TILE 128
#define BKK  64
#define BM256 256
#define BN256 256

typedef __attribute__((ext_vector_type(8))) __bf16 bfrag8;
typedef __attribute__((ext_vector_type(4))) float  f32x4;
typedef __attribute__((ext_vector_type(8))) short  s8v;

#define GLOBAL_AS(p) ((const __attribute__((address_space(1))) void*)(p))
#define LDS_AS(p)    ((__attribute__((address_space(3))) void*)(p))

__device__ inline unsigned short f2bf(float f) {
    union { float f; unsigned u; } v; v.f = f;
    unsigned r = v.u + 0x7FFFu + ((v.u >> 16) & 1u);   // RNE
    return (unsigned short)(r >> 16);
}
__device__ inline float bf2f(unsigned short u) {
    union { unsigned u; float f; } v; v.u = ((unsigned)u) << 16;
    return v.f;
}

// W storage dtype: f32 storage of fp8-grid values => even uint16s all zero.
__device__ inline int detect_w_f32(const void* w) {
    const unsigned short* u = (const unsigned short*)w;
    unsigned nz = 0;
#pragma unroll
    for (int i = 0; i < 64; ++i) nz |= u[2 * i];
    return nz == 0 ? 1 : 0;
}

__global__ void FP8FL_cvt_x(const float* __restrict__ x, short* __restrict__ xb, long n) {
    long i = ((long)blockIdx.x * blockDim.x + threadIdx.x) * 8;
    if (i >= n) return;
    float4 a = *(const float4*)(x + i);
    float4 b = *(const float4*)(x + i + 4);
    s8v r;
    r[0] = (short)f2bf(a.x); r[1] = (short)f2bf(a.y);
    r[2] = (short)f2bf(a.z); r[3] = (short)f2bf(a.w);
    r[4] = (short)f2bf(b.x); r[5] = (short)f2bf(b.y);
    r[6] = (short)f2bf(b.z); r[7] = (short)f2bf(b.w);
    *(s8v*)(xb + i) = r;
}

__global__ void FP8FL_cvt_w(const void* __restrict__ w, short* __restrict__ wb,
                            const float* __restrict__ scale_p, long n) {
    __shared__ int sdt;
    if (threadIdx.x == 0) sdt = detect_w_f32(w);
    __syncthreads();
    long i = ((long)blockIdx.x * blockDim.x + threadIdx.x) * 8;
    if (i >= n) return;
    const float s = scale_p[0];
    s8v r;
    if (sdt) {
        const float* wf = (const float*)w;
        float4 a = *(const float4*)(wf + i);
        float4 b = *(const float4*)(wf + i + 4);
        r[0] = (short)f2bf(a.x * s); r[1] = (short)f2bf(a.y * s);
        r[2] = (short)f2bf(a.z * s); r[3] = (short)f2bf(a.w * s);
        r[4] = (short)f2bf(b.x * s); r[5] = (short)f2bf(b.y * s);
        r[6] = (short)f2bf(b.z * s); r[7] = (short)f2bf(b.w * s);
    } else {
        const unsigned short* wu = (const unsigned short*)w;
        s8v v = *(const s8v*)(wu + i);
#pragma unroll
        for (int j = 0; j < 8; ++j)
            r[j] = (short)f2bf(bf2f((unsigned short)v[j]) * s);
    }
    *(s8v*)(wb + i) = r;
}

// ---------------- 256x256 GEMM, 1 phase / K-tile ----------------
// LDS: A slab p: d*65536 + p*16384 ; B slab p: d*65536 + 32768 + p*16384.
// Slab = [256 rows][4 slots x 16B], phys slot = logical ^ ((row>>1)&3),
// staged linearly with inverse-swizzled global source (rule #21).
__device__ inline void stage_tile256(const short* __restrict__ A, const short* __restrict__ B,
                                     long row0, long col0, int K, int kc,
                                     char* __restrict__ lds, int d, int wid, int lane) {
#pragma unroll
    for (int p = 0; p < 2; ++p) {
        char* Asl = lds + d * 65536 + p * 16384;
        char* Bsl = lds + d * 65536 + 32768 + p * 16384;
        int kk = kc + p * 32;
#pragma unroll
        for (int i = 0; i < 2; ++i) {
            int pc = i * 512 + wid * 64 + lane;
            int r  = pc >> 2;
            int j  = (pc & 3) ^ ((r >> 1) & 3);
            const short* ga = A + (size_t)(row0 + r) * K + kk + j * 8;
            const short* gb = B + (size_t)(col0 + r) * K + kk + j * 8;
            char* da = Asl + (i * 512 + wid * 64) * 16;   // wave-uniform base
            char* db = Bsl + (i * 512 + wid * 64) * 16;
            __builtin_amdgcn_global_load_lds(GLOBAL_AS(ga), LDS_AS(da), 16, 0, 0);
            __builtin_amdgcn_global_load_lds(GLOBAL_AS(gb), LDS_AS(db), 16, 0, 0);
        }
    }
}

__global__ __launch_bounds__(512, 2)
void FP8FL_gemm256(const short* __restrict__ A, const short* __restrict__ B,
                   const float* __restrict__ bias, float* __restrict__ C,
                   int M, int N, int K) {
    __shared__ char lds[131072];

    const int tid  = threadIdx.x;
    const int lane = tid & 63;
    const int wid  = tid >> 6;

    const int nwg = gridDim.x;
    const int bid = blockIdx.x;
    const int wg  = (nwg % 8 == 0) ? (bid % 8) * (nwg / 8) + (bid / 8) : bid;

    const int tiles_n = N / BN256;
    const long row0 = (long)(wg / tiles_n) * BM256;
    const long col0 = (long)(wg % tiles_n) * BN256;

    const int wm = wid >> 2, wn = wid & 3;      // 2x4 wave grid, 128x64 out each
    const int rl = lane & 15, g = lane >> 4;

    f32x4 acc[8][4];
#pragma unroll
    for (int m = 0; m < 8; ++m)
#pragma unroll
        for (int n = 0; n < 4; ++n) acc[m][n] = (f32x4){0.f, 0.f, 0.f, 0.f};

    const int NT = K / BKK;

    // Prologue: stage tile 0 into buffer 0; full drain + barrier.
    stage_tile256(A, B, row0, col0, K, 0, lds, 0, wid, lane);
    __syncthreads();

    for (int t = 0; t < NT; ++t) {
        const int d = t & 1;
        const char* base = lds + d * 65536;

        // Issue ALL fragment reads (both slabs) up front: slab-1 reads drain
        // under slab-0 MFMA via compiler partial lgkmcnt.
        bfrag8 af[2][8], bf[2][4];
#pragma unroll
        for (int p = 0; p < 2; ++p) {
            const char* Asl = base + p * 16384;
            const char* Bsl = base + 32768 + p * 16384;
#pragma unroll
            for (int m = 0; m < 8; ++m) {
                int r  = wm * 128 + m * 16 + rl;
                int sl = g ^ ((r >> 1) & 3);
                af[p][m] = *(const bfrag8*)(Asl + (r * 4 + sl) * 16);
            }
#pragma unroll
            for (int n = 0; n < 4; ++n) {
                int r  = wn * 64 + n * 16 + rl;
                int sl = g ^ ((r >> 1) & 3);
                bf[p][n] = *(const bfrag8*)(Bsl + (r * 4 + sl) * 16);
            }
        }

        // Prefetch next tile into the other buffer (full-tile vmcnt slack).
        if (t + 1 < NT)
            stage_tile256(A, B, row0, col0, K, (t + 1) * BKK, lds, d ^ 1, wid, lane);

        __builtin_amdgcn_s_setprio(1);
#pragma unroll
        for (int p = 0; p < 2; ++p)
#pragma unroll
            for (int m = 0; m < 8; ++m)
#pragma unroll
                for (int n = 0; n < 4; ++n)
                    acc[m][n] = __builtin_amdgcn_mfma_f32_16x16x32_bf16(af[p][m], bf[p][n], acc[m][n], 0, 0, 0);
        __builtin_amdgcn_s_setprio(0);

        // One barrier per tile: drains vmcnt(0) (stage done) + syncs waves.
        __syncthreads();
    }

    // Epilogue: C/D layout col = lane&15, row = (lane>>4)*4 + reg  [m89/m91]
    float bv[4];
#pragma unroll
    for (int n = 0; n < 4; ++n) bv[n] = bias[col0 + wn * 64 + n * 16 + rl];
#pragma unroll
    for (int m = 0; m < 8; ++m) {
#pragma unroll
        for (int jj = 0; jj < 4; ++jj) {
            long r = row0 + wm * 128 + m * 16 + g * 4 + jj;
            float* cp = C + r * (long)N + col0 + wn * 64 + rl;
#pragma unroll
            for (int n = 0; n < 4; ++n) cp[n * 16] = acc[m][n][jj] + bv[n];
        }
    }
}

// ---------------- m97-style 128^2 GEMM (R5, verified) — fallback ----------------
__global__ void FP8FL_gemm(const short* __restrict__ A, const short* __restrict__ B,
                           const float* __restrict__ bias, float* __restrict__ C,
                           int M, int N, int K) {
    __shared__ short As[TILE * BKK];
    __shared__ short Bs[TILE * BKK];

    const int tid  = threadIdx.x;
    const int lane = tid & 63;
    const int wid  = tid >> 6;

    const int nwg = gridDim.x;
    const int bid = blockIdx.x;
    const int wg  = (nwg % 8 == 0) ? (bid % 8) * (nwg / 8) + (bid / 8) : bid;

    const int tiles_n = N / TILE;
    const long row0 = (long)(wg / tiles_n) * TILE;
    const long col0 = (long)(wg % tiles_n) * TILE;

    const int wm = wid >> 1, wn = wid & 1;

    f32x4 acc[4][4];
#pragma unroll
    for (int i = 0; i < 4; ++i)
#pragma unroll
        for (int j = 0; j < 4; ++j) acc[i][j] = (f32x4){0.f, 0.f, 0.f, 0.f};

    const int rl = lane & 15;
    const int g  = lane >> 4;

    for (int k0 = 0; k0 < K; k0 += BKK) {
        __syncthreads();
#pragma unroll
        for (int i = 0; i < 4; ++i) {
            int c  = i * 256 + tid;
            int r  = c >> 3;
            int ls = c & 7;
            const short* ga = A + ((size_t)(row0 + r) * K + k0 + ls * 8);
            const short* gb = B + ((size_t)(col0 + r) * K + k0 + ls * 8);
            int ldsoff = (i * 256 + wid * 64) * 16;
            __builtin_amdgcn_global_load_lds(GLOBAL_AS(ga), LDS_AS((char*)As + ldsoff), 16, 0, 0);
            __builtin_amdgcn_global_load_lds(GLOBAL_AS(gb), LDS_AS((char*)Bs + ldsoff), 16, 0, 0);
        }
        __syncthreads();

#pragma unroll
        for (int kk = 0; kk < 2; ++kk) {
            bfrag8 af[4], bfr[4];
            const int lsk = kk * 4 + g;
#pragma unroll
            for (int m = 0; m < 4; ++m) {
                int r  = wm * 64 + m * 16 + rl;
                af[m] = *(const bfrag8*)&As[r * 64 + lsk * 8];
            }
#pragma unroll
            for (int n = 0; n < 4; ++n) {
                int r  = wn * 64 + n * 16 + rl;
                bfr[n] = *(const bfrag8*)&Bs[r * 64 + lsk * 8];
            }
#pragma unroll
            for (int m = 0; m < 4; ++m)
#pragma unroll
                for (int n = 0; n < 4; ++n)
                    acc[m][n] = __builtin_amdgcn_mfma_f32_16x16x32_bf16(af[m], bfr[n], acc[m][n], 0, 0, 0);
        }
    }

    float bv[4];
#pragma unroll
    for (int n = 0; n < 4; ++n) bv[n] = bias[col0 + wn * 64 + n * 16 + rl];
#pragma unroll
    for (int m = 0; m < 4; ++m) {
#pragma unroll
        for (int j = 0; j < 4; ++j) {
            long r = row0 + wm * 64 + m * 16 + g * 4 + j;
            float* cp = C + r * (long)N + col0 + wn * 64 + rl;
#pragma unroll
            for (int n = 0; n < 4; ++n) cp[n * 16] = acc[m][n][j] + bv[n];
        }
    }
}

// Fused GEMM (ws too small): reads x (f32) and W (bf16/f32) directly. R5-verified path.
__global__ void FP8FL_gemm_fused(const float* __restrict__ X, const void* __restrict__ W,
                                 const float* __restrict__ scale_p,
                                 const float* __restrict__ bias, float* __restrict__ C,
                                 int M, int N, int K) {
    __shared__ short As[TILE * BKK];
    __shared__ short Bs[TILE * BKK];
    __shared__ int sdt;

    const int tid  = threadIdx.x;
    const int lane = tid & 63;
    const int wid  = tid >> 6;

    if (tid == 0) sdt = detect_w_f32(W);
    __syncthreads();
    const int wdt = sdt;
    const float s = scale_p[0];

    const int nwg = gridDim.x;
    const int bid = blockIdx.x;
    const int wg  = (nwg % 8 == 0) ? (bid % 8) * (nwg / 8) + (bid / 8) : bid;

    const int tiles_n = N / TILE;
    const long row0 = (long)(wg / tiles_n) * TILE;
    const long col0 = (long)(wg % tiles_n) * TILE;

    const int wm = wid >> 1, wn = wid & 1;

    f32x4 acc[4][4];
#pragma unroll
    for (int i = 0; i < 4; ++i)
#pragma unroll
        for (int j = 0; j < 4; ++j) acc[i][j] = (f32x4){0.f, 0.f, 0.f, 0.f};

    const int rl = lane & 15;
    const int g  = lane >> 4;

    for (int k0 = 0; k0 < K; k0 += BKK) {
        s8v va[4], vb[4];
#pragma unroll
        for (int i = 0; i < 4; ++i) {
            int c  = i * 256 + tid;
            int r  = c >> 3;
            int ls = c & 7;
            {
                const float* xp = X + ((size_t)(row0 + r) * K + k0 + ls * 8);
                float4 a = *(const float4*)xp;
                float4 b = *(const float4*)(xp + 4);
                s8v t;
                t[0] = (short)f2bf(a.x); t[1] = (short)f2bf(a.y);
                t[2] = (short)f2bf(a.z); t[3] = (short)f2bf(a.w);
                t[4] = (short)f2bf(b.x); t[5] = (short)f2bf(b.y);
                t[6] = (short)f2bf(b.z); t[7] = (short)f2bf(b.w);
                va[i] = t;
            }
            {
                size_t off = (size_t)(col0 + r) * K + k0 + ls * 8;
                s8v t;
                if (wdt) {
                    const float* wp = (const float*)W + off;
                    float4 a = *(const float4*)wp;
                    float4 b = *(const float4*)(wp + 4);
                    t[0] = (short)f2bf(a.x * s); t[1] = (short)f2bf(a.y * s);
                    t[2] = (short)f2bf(a.z * s); t[3] = (short)f2bf(a.w * s);
                    t[4] = (short)f2bf(b.x * s); t[5] = (short)f2bf(b.y * s);
                    t[6] = (short)f2bf(b.z * s); t[7] = (short)f2bf(b.w * s);
                } else {
                    const unsigned short* wp = (const unsigned short*)W + off;
                    s8v v = *(const s8v*)wp;
#pragma unroll
                    for (int j = 0; j < 8; ++j)
                        t[j] = (short)f2bf(bf2f((unsigned short)v[j]) * s);
                }
                vb[i] = t;
            }
        }
        __syncthreads();
#pragma unroll
        for (int i = 0; i < 4; ++i) {
            int c = i * 256 + tid;
            *(s8v*)((char*)As + (size_t)c * 16) = va[i];
            *(s8v*)((char*)Bs + (size_t)c * 16) = vb[i];
        }
        __syncthreads();

#pragma unroll
        for (int kk = 0; kk < 2; ++kk) {
            bfrag8 af[4], bfr[4];
            const int lsk = kk * 4 + g;
#pragma unroll
            for (int m = 0; m < 4; ++m) {
                int r  = wm * 64 + m * 16 + rl;
                af[m] = *(const bfrag8*)&As[r * 64 + lsk * 8];
            }
#pragma unroll
            for (int n = 0; n < 4; ++n) {
                int r  = wn * 64 + n * 16 + rl;
                bfr[n] = *(const bfrag8*)&Bs[r * 64 + lsk * 8];
            }
#pragma unroll
            for (int m = 0; m < 4; ++m)
#pragma unroll
                for (int n = 0; n < 4; ++n)
                    acc[m][n] = __builtin_amdgcn_mfma_f32_16x16x32_bf16(af[m], bfr[n], acc[m][n], 0, 0, 0);
        }
    }

    float bv[4];
#pragma unroll
    for (int n = 0; n < 4; ++n) bv[n] = bias[col0 + wn * 64 + n * 16 + rl];
#pragma unroll
    for (int m = 0; m < 4; ++m) {
#pragma unroll
        for (int j = 0; j < 4; ++j) {
            long r = row0 + wm * 64 + m * 16 + g * 4 + j;
            float* cp = C + r * (long)N + col0 + wn * 64 + rl;
#pragma unroll
            for (int n = 0; n < 4; ++n) cp[n * 16] = acc[m][n][j] + bv[n];
        }
    }
}

// Last-resort fallback (odd dims).
__global__ void FP8FL_naive(const float* __restrict__ x, const void* __restrict__ w,
                            const float* __restrict__ scale_p, const float* __restrict__ bias,
                            float* __restrict__ out, int M, int N, int K) {
    __shared__ int sdt;
    if (threadIdx.x == 0) sdt = detect_w_f32(w);
    __syncthreads();
    long o = (long)blockIdx.x * blockDim.x + threadIdx.x;
    if (o >= (long)M * N) return;
    int m = (int)(o / N), n = (int)(o % N);
    const float* xr = x + (size_t)m * K;
    float acc = 0.f;
    if (sdt) {
        const float* wr = (const float*)w + (size_t)n * K;
        for (int k = 0; k < K; ++k) acc += xr[k] * wr[k];
    } else {
        const unsigned short* wr = (const unsigned short*)w + (size_t)n * K;
        for (int k = 0; k < K; ++k) acc += xr[k] * bf2f(wr[k]);
    }
    out[o] = acc * scale_p[0] + bias[n];
}

extern "C" void kernel_launch(void* const* d_in, const int* in_sizes, int n_in,
                              void* d_out, int out_size, void* d_ws, size_t ws_size,
                              hipStream_t stream) {
    const float* x     = (const float*)d_in[0];
    const void*  w     = d_in[1];
    const float* scale = (const float*)d_in[2];
    const float* bias  = (const float*)d_in[3];
    float*       out   = (float*)d_out;

    const int N = in_sizes[3];
    const int K = in_sizes[1] / N;
    const int M = in_sizes[0] / K;

    const size_t need = (size_t)M * K * 2 + (size_t)N * K * 2;
    const bool ws_ok   = ws_size >= need;
    const bool dims256 = (M % BM256 == 0) && (N % BN256 == 0) && (K % BKK == 0);
    const bool dims128 = (M % TILE == 0) && (N % TILE == 0) && (K % BKK == 0);

    if (ws_ok && (dims256 || dims128)) {
        short* xb = (short*)d_ws;
        short* wb = (short*)((char*)d_ws + (size_t)M * K * 2);
        long nx = (long)M * K;
        long nw = (long)N * K;
        FP8FL_cvt_x<<<(int)((nx / 8 + 255) / 256), 256, 0, stream>>>(x, xb, nx);
        FP8FL_cvt_w<<<(int)((nw / 8 + 255) / 256), 256, 0, stream>>>(w, wb, scale, nw);
        if (dims256) {
            int grid = (M / BM256) * (N / BN256);
            FP8FL_gemm256<<<grid, 512, 0, stream>>>(xb, wb, bias, out, M, N, K);
        } else {
            int grid = (M / TILE) * (N / TILE);
            FP8FL_gemm<<<grid, 256, 0, stream>>>(xb, wb, bias, out, M, N, K);
        }
    } else if (dims128) {
        int grid = (M / TILE) * (N / TILE);
        FP8FL_gemm_fused<<<grid, 256, 0, stream>>>(x, w, scale, bias, out, M, N, K);
    } else {
        long total = (long)M * N;
        FP8FL_naive<<<(int)((total + 255) / 256), 256, 0, stream>>>(x, w, scale, bias, out, M, N, K);
    }
}